// Round 16
// baseline (276.578 us; speedup 1.0000x reference)
//
#include <hip/hip_runtime.h>
#include <math.h>

#define NN 50000
#define NE 800000
#define KD 128
#define CAP 64                      /* fixed bin capacity; P(row>64 edges) ~ 3e-14 */
#define SLOPE 0.22916666666666666f  /* 11/48, torch RReLU eval negative slope */

__device__ __forceinline__ void fma4(float s, const float4& q, float4& acc){
  acc.x = fmaf(s, q.x, acc.x); acc.y = fmaf(s, q.y, acc.y);
  acc.z = fmaf(s, q.z, acc.z); acc.w = fmaf(s, q.w, acc.w);
}

// dot of a VGPR-cached matrix row (32 float4 over k) with a 128-float LDS
// vector read as float4 broadcasts. 4 partial accumulators break the chain.
__device__ __forceinline__ float dotS(const float4* mrow, const float* sV){
  const float4* v4 = (const float4*)sV;
  float a0=0.f, a1=0.f, a2=0.f, a3=0.f;
#pragma unroll
  for (int kq = 0; kq < 32; ++kq){
    float4 m = mrow[kq];
    float4 q = v4[kq];                 // wave-uniform broadcast
    a0 = fmaf(m.x, q.x, a0);
    a1 = fmaf(m.y, q.y, a1);
    a2 = fmaf(m.z, q.z, a2);
    a3 = fmaf(m.w, q.w, a3);
  }
  return (a0 + a1) + (a2 + a3);
}

// ---------------------------------------------------------------------------
// Evolve (fused, column-separable): W_e = GRU^4(W0) for both layers.
// Grid: 256 blocks = layer(2) x column(128) -> one block per CU.
// ---------------------------------------------------------------------------
__global__ __launch_bounds__(256, 1) void evolve_fused_kernel(
    const float* __restrict__ g1W, const float* __restrict__ g1U,
    const float* __restrict__ g2W, const float* __restrict__ g2U,
    const float* __restrict__ g1b, const float* __restrict__ g2b,
    const float* __restrict__ W1,  const float* __restrict__ W2,
    float* __restrict__ We1, float* __restrict__ We2)
{
  __shared__ __align__(16) float sQ[128];    // Q[:, col]
  __shared__ __align__(16) float sRQ[128];   // r*Q
  __shared__ __align__(16) float sT2b[128];  // gU2 @ rq
  const int layer = blockIdx.x >> 7;
  const int col = blockIdx.x & 127;
  const int t = threadIdx.x;
  const int r = t & 127;
  const int h = t >> 7;
  const float4* gW4 = (const float4*)(layer ? g2W : g1W);
  const float4* gU4 = (const float4*)(layer ? g2U : g1U);
  const float*  gb  = layer ? g2b : g1b;
  const float*  W0  = layer ? W2  : W1;
  float* We = layer ? We2 : We1;

  // cache matrix rows in VGPRs (fully unrolled -> static reg indexing)
  float4 mA[32], mB[32];
  if (h == 0){
#pragma unroll
    for (int kq = 0; kq < 32; ++kq){
      float4 a = gW4[0*4096 + r*32 + kq];
      float4 u = gU4[0*4096 + r*32 + kq];
      a.x+=u.x; a.y+=u.y; a.z+=u.z; a.w+=u.w;
      mA[kq] = a;
      mB[kq] = gW4[2*4096 + r*32 + kq];
    }
  } else {
#pragma unroll
    for (int kq = 0; kq < 32; ++kq){
      float4 a = gW4[1*4096 + r*32 + kq];
      float4 u = gU4[1*4096 + r*32 + kq];
      a.x+=u.x; a.y+=u.y; a.z+=u.z; a.w+=u.w;
      mA[kq] = a;
      mB[kq] = gU4[2*4096 + r*32 + kq];
    }
  }
  const float bX = gb[(h ? 1 : 0)*16384 + r*128 + col];
  const float bY = (h == 0) ? gb[2*16384 + r*128 + col] : 0.f;

  if (h == 0) sQ[r] = W0[r*128 + col];
  __syncthreads();

  for (int it = 0; it < 4; ++it){
    // pass 1: h0 -> T0[r] (kept in reg), h1 -> T1[r] -> sRQ
    float tA = dotS(mA, sQ);
    if (h == 1){
      float rr = 1.f/(1.f + expf(-(tA + bX)));
      sRQ[r] = rr * sQ[r];
    }
    __syncthreads();
    // pass 2: h0 -> t2a = gW2@q, h1 -> t2b = gU2@rq
    float tB = dotS(mB, (h == 0) ? sQ : sRQ);
    if (h == 1) sT2b[r] = tB;
    __syncthreads();
    if (h == 0){
      float z = 1.f/(1.f + expf(-(tA + bX)));
      float q = sQ[r];
      sQ[r] = (1.f - z)*q + z*tanhf(tB + sT2b[r] + bY);
    }
    __syncthreads();
  }
  if (h == 0) We[r*128 + col] = sQ[r];
}

// ---------------------------------------------------------------------------
// GEMM: Y[nrows x 128] = X[nrows x 128] @ W[128 x 128], fp32 vector ALU.
// Grid 196 blocks; grid-strides over 128-row tiles, stages W once.
// Inner loop k-chunked by 4: X read as ds_read_b128 (4 k's at once) ->
// 12 b128 LDS ops per 4k instead of 8 b128 + 16 b32 (LDS-issue-bound fix).
// FMA order per output element unchanged (k ascending) -> bitwise identical.
// ---------------------------------------------------------------------------
__device__ __forceinline__ int wperm(int c){
  return ((c >> 1) & 7) | ((c & 1) << 3) | ((c >> 4) << 4);
}

#define GEMM_NB 196

#define ROWFMA(RR, XV) \
  acc[RR][0]=fmaf(XV,wa.x,acc[RR][0]); acc[RR][1]=fmaf(XV,wa.y,acc[RR][1]); \
  acc[RR][2]=fmaf(XV,wa.z,acc[RR][2]); acc[RR][3]=fmaf(XV,wa.w,acc[RR][3]); \
  acc[RR][4]=fmaf(XV,wb.x,acc[RR][4]); acc[RR][5]=fmaf(XV,wb.y,acc[RR][5]); \
  acc[RR][6]=fmaf(XV,wb.z,acc[RR][6]); acc[RR][7]=fmaf(XV,wb.w,acc[RR][7]);

#define GSTEP(J, COMP) { \
  const int kk = kq*4 + J; \
  float4 wa = sW4[kk*32 + slotA]; \
  float4 wb = sW4[kk*32 + slotB]; \
  ROWFMA(0, x0.COMP) ROWFMA(1, x1.COMP) ROWFMA(2, x2.COMP) ROWFMA(3, x3.COMP) }

__global__ __launch_bounds__(512) void gemm_kernel(
    const float* __restrict__ X, const float* __restrict__ W,
    float* __restrict__ Y, int nrows)
{
  __shared__ float4 sX4[128*33];   // row stride 132 floats
  __shared__ float4 sW4[128*32];
  const int tid = threadIdx.x;
  const int rg = tid >> 4;
  const int cg_ = tid & 15;

  const float4* X4 = (const float4*)X;
  const float4* W4 = (const float4*)W;
#pragma unroll
  for (int s = 0; s < 8; ++s){
    int g4 = tid + 512*s;
    int k = g4 >> 5, c = g4 & 31;
    sW4[k*32 + wperm(c)] = W4[g4];
  }

  const float* sXf = (const float*)sX4;
  const int slotA = (cg_ & 7) | ((cg_ >> 3) << 4);
  const int slotB = slotA | 8;
  const int ntiles = (nrows + 127) >> 7;
  float4* Y4 = (float4*)Y;

  for (int tile = blockIdx.x; tile < ntiles; tile += gridDim.x){
    const int rbase = tile << 7;
    if (tile != blockIdx.x) __syncthreads();   // prior compute done before restage
#pragma unroll
    for (int s = 0; s < 8; ++s){
      int g4 = tid + 512*s;
      int r = g4 >> 5, c = g4 & 31;
      float4 v = make_float4(0.f,0.f,0.f,0.f);
      int row = rbase + r;
      if (row < nrows) v = X4[(size_t)row*32 + c];
      sX4[r*33 + c] = v;
    }
    __syncthreads();

    float acc[4][8];
#pragma unroll
    for (int a = 0; a < 4; ++a)
#pragma unroll
      for (int b = 0; b < 8; ++b) acc[a][b] = 0.f;

#pragma unroll 4
    for (int kq = 0; kq < 32; ++kq){
      float4 x0 = *(const float4*)(sXf + (rg*4+0)*132 + kq*4);
      float4 x1 = *(const float4*)(sXf + (rg*4+1)*132 + kq*4);
      float4 x2 = *(const float4*)(sXf + (rg*4+2)*132 + kq*4);
      float4 x3 = *(const float4*)(sXf + (rg*4+3)*132 + kq*4);
      GSTEP(0, x) GSTEP(1, y) GSTEP(2, z) GSTEP(3, w)
    }

#pragma unroll
    for (int rr = 0; rr < 4; ++rr){
      int row = rbase + rg*4 + rr;
      if (row < nrows){
        Y4[(size_t)row*32 + cg_*2 + 0] = make_float4(acc[rr][0],acc[rr][1],acc[rr][2],acc[rr][3]);
        Y4[(size_t)row*32 + cg_*2 + 1] = make_float4(acc[rr][4],acc[rr][5],acc[rr][6],acc[rr][7]);
      }
    }
  }
}

// ---------------------------------------------------------------------------
// Edge binning into fixed-CAP bins, atomic/store split (no scans).
// ---------------------------------------------------------------------------
__global__ __launch_bounds__(256) void hist_kernel(const int* __restrict__ row,
                                                   int* __restrict__ counts, int* __restrict__ slot){
  int base = blockIdx.x*1024 + threadIdx.x;
#pragma unroll
  for (int s = 0; s < 4; ++s){
    int e = base + 256*s;
    if (e < NE){
      int r = row[e];
      int rk = atomicAdd(&counts[r], 1);
      slot[e] = (rk < CAP) ? ((r << 6) + rk) : -1;
    }
  }
}

__global__ __launch_bounds__(256) void scatter_kernel(const int* __restrict__ col,
                                                      const float* __restrict__ val, const int* __restrict__ slot,
                                                      int2* __restrict__ sEdge){
  int base = blockIdx.x*1024 + threadIdx.x;
  int e[4], sl[4];
  bool ok[4];
#pragma unroll
  for (int s = 0; s < 4; ++s){
    e[s] = base + 256*s;
    ok[s] = e[s] < NE;
    sl[s] = ok[s] ? slot[e[s]] : -1;
  }
#pragma unroll
  for (int s = 0; s < 4; ++s){
    if (sl[s] >= 0){
      int2 pk;
      pk.x = col[e[s]];
      pk.y = __float_as_int(val[e[s]]);
      sEdge[sl[s]] = pk;
    }
  }
}

// ---------------------------------------------------------------------------
// SpMM: 2 rows per wave. Half-wave (32 lanes x float4) covers a 512B row.
// 8-deep unroll keeps 8KB of gathers in flight per wave. Bins are contiguous
// CAP-slot runs at r*CAP. rrelu fused into writeback.
// ---------------------------------------------------------------------------
__global__ __launch_bounds__(256) void spmm_kernel(const int* __restrict__ counts, const int2* __restrict__ sEdge,
                                                   const float* __restrict__ Y, float* __restrict__ out){
  const int w = threadIdx.x >> 6;          // wave in block (0..3)
  const int lane = threadIdx.x & 63;
  const int half = lane >> 5;              // which row of the pair
  const int l32 = lane & 31;               // float4 slot within row
  const int r = blockIdx.x*8 + w*2 + half;
  if (r >= NN) return;
  int cnt = counts[r];
  if (cnt > CAP) cnt = CAP;
  const int e0 = r << 6;
  const int e1 = e0 + cnt;
  const float4* __restrict__ Y4 = (const float4*)Y;
  float4 acc = make_float4(0.f, 0.f, 0.f, 0.f);
  int e = e0;
  for (; e + 8 <= e1; e += 8){
    int2 p0 = sEdge[e+0], p1 = sEdge[e+1], p2 = sEdge[e+2], p3 = sEdge[e+3];
    int2 p4 = sEdge[e+4], p5 = sEdge[e+5], p6 = sEdge[e+6], p7 = sEdge[e+7];
    float4 y0 = Y4[(size_t)p0.x*32 + l32];
    float4 y1 = Y4[(size_t)p1.x*32 + l32];
    float4 y2 = Y4[(size_t)p2.x*32 + l32];
    float4 y3 = Y4[(size_t)p3.x*32 + l32];
    float4 y4 = Y4[(size_t)p4.x*32 + l32];
    float4 y5 = Y4[(size_t)p5.x*32 + l32];
    float4 y6 = Y4[(size_t)p6.x*32 + l32];
    float4 y7 = Y4[(size_t)p7.x*32 + l32];
    fma4(__int_as_float(p0.y), y0, acc);
    fma4(__int_as_float(p1.y), y1, acc);
    fma4(__int_as_float(p2.y), y2, acc);
    fma4(__int_as_float(p3.y), y3, acc);
    fma4(__int_as_float(p4.y), y4, acc);
    fma4(__int_as_float(p5.y), y5, acc);
    fma4(__int_as_float(p6.y), y6, acc);
    fma4(__int_as_float(p7.y), y7, acc);
  }
  for (; e + 4 <= e1; e += 4){
    int2 p0 = sEdge[e+0], p1 = sEdge[e+1], p2 = sEdge[e+2], p3 = sEdge[e+3];
    float4 y0 = Y4[(size_t)p0.x*32 + l32];
    float4 y1 = Y4[(size_t)p1.x*32 + l32];
    float4 y2 = Y4[(size_t)p2.x*32 + l32];
    float4 y3 = Y4[(size_t)p3.x*32 + l32];
    fma4(__int_as_float(p0.y), y0, acc);
    fma4(__int_as_float(p1.y), y1, acc);
    fma4(__int_as_float(p2.y), y2, acc);
    fma4(__int_as_float(p3.y), y3, acc);
  }
  for (; e < e1; ++e){
    int2 pk = sEdge[e];
    float4 y = Y4[(size_t)pk.x*32 + l32];
    fma4(__int_as_float(pk.y), y, acc);
  }
  float4 o;
  o.x = (acc.x >= 0.f) ? acc.x : acc.x * SLOPE;
  o.y = (acc.y >= 0.f) ? acc.y : acc.y * SLOPE;
  o.z = (acc.z >= 0.f) ? acc.z : acc.z * SLOPE;
  o.w = (acc.w >= 0.f) ? acc.w : acc.w * SLOPE;
  ((float4*)out)[(size_t)r*32 + l32] = o;
}

// ---------------------------------------------------------------------------
extern "C" void kernel_launch(void* const* d_in, const int* in_sizes, int n_in,
                              void* d_out, int out_size, void* d_ws, size_t ws_size,
                              hipStream_t stream)
{
  const float* features = (const float*)d_in[0];
  const int*   adj_row  = (const int*)d_in[1];
  const int*   adj_col  = (const int*)d_in[2];
  const float* adj_val  = (const float*)d_in[3];
  const float* W1  = (const float*)d_in[4];
  const float* g1W = (const float*)d_in[5];
  const float* g1U = (const float*)d_in[6];
  const float* g1b = (const float*)d_in[7];
  const float* W2  = (const float*)d_in[8];
  const float* g2W = (const float*)d_in[9];
  const float* g2U = (const float*)d_in[10];
  const float* g2b = (const float*)d_in[11];

  // only timestep T-1 ever reaches the output
  const float* feat3 = features + (size_t)3*NN*KD;
  const int*   row3  = adj_row + (size_t)3*NE;
  const int*   col3  = adj_col + (size_t)3*NE;
  const float* val3  = adj_val + (size_t)3*NE;

  float* ws    = (float*)d_ws;
  float* W1e   = ws;                      // 16384 f
  float* W2e   = W1e + 16384;             // 16384 f
  int* counts  = (int*)(W2e + 16384);     // 50000 (padded 50016)
  int* slot    = counts + 50016;          // 800000
  int2* sEdge  = (int2*)(slot + NE);      // 50000*64 x 8B = 25.6 MB (8B-aligned)
  float* XW    = (float*)(sEdge + (size_t)NN*CAP);  // 25.6 MB
  float* outF  = (float*)d_out;

  hipMemsetAsync(counts, 0, NN*sizeof(int), stream);
  hist_kernel<<<(NE + 1023)/1024, 256, 0, stream>>>(row3, counts, slot);
  scatter_kernel<<<(NE + 1023)/1024, 256, 0, stream>>>(col3, val3, slot, sEdge);

  // GRU^4 on both layers' weights: ONE kernel, one block per (layer, column).
  evolve_fused_kernel<<<256, 256, 0, stream>>>(g1W,g1U,g2W,g2U,g1b,g2b, W1,W2, W1e,W2e);

  gemm_kernel<<<GEMM_NB, 512, 0, stream>>>(feat3, W1e, XW, NN);            // X3 @ W1e
  spmm_kernel<<<(NN + 7)/8, 256, 0, stream>>>(counts, sEdge, XW, outF);    // h1 -> d_out
  gemm_kernel<<<GEMM_NB, 512, 0, stream>>>(outF, W2e, XW, NN);             // h1 @ W2e
  spmm_kernel<<<(NN + 7)/8, 256, 0, stream>>>(counts, sEdge, XW, outF);    // final -> d_out
}

// Round 17
// 272.503 us; speedup vs baseline: 1.0150x; 1.0150x over previous
//
#include <hip/hip_runtime.h>
#include <math.h>

#define NN 50000
#define NE 800000
#define KD 128
#define CAP 64                      /* fixed bin capacity; P(row>64 edges) ~ 3e-14 */
#define SLOPE 0.22916666666666666f  /* 11/48, torch RReLU eval negative slope */

__device__ __forceinline__ void fma4(float s, const float4& q, float4& acc){
  acc.x = fmaf(s, q.x, acc.x); acc.y = fmaf(s, q.y, acc.y);
  acc.z = fmaf(s, q.z, acc.z); acc.w = fmaf(s, q.w, acc.w);
}

// dot of a VGPR-cached matrix row (32 float4 over k) with a 128-float LDS
// vector read as float4 broadcasts. 4 partial accumulators break the chain.
__device__ __forceinline__ float dotS(const float4* mrow, const float* sV){
  const float4* v4 = (const float4*)sV;
  float a0=0.f, a1=0.f, a2=0.f, a3=0.f;
#pragma unroll
  for (int kq = 0; kq < 32; ++kq){
    float4 m = mrow[kq];
    float4 q = v4[kq];                 // wave-uniform broadcast
    a0 = fmaf(m.x, q.x, a0);
    a1 = fmaf(m.y, q.y, a1);
    a2 = fmaf(m.z, q.z, a2);
    a3 = fmaf(m.w, q.w, a3);
  }
  return (a0 + a1) + (a2 + a3);
}

// ---------------------------------------------------------------------------
// Evolve (fused, column-separable): W_e = GRU^4(W0) for both layers.
// Grid: 256 blocks = layer(2) x column(128) -> one block per CU.
// ---------------------------------------------------------------------------
__global__ __launch_bounds__(256, 1) void evolve_fused_kernel(
    const float* __restrict__ g1W, const float* __restrict__ g1U,
    const float* __restrict__ g2W, const float* __restrict__ g2U,
    const float* __restrict__ g1b, const float* __restrict__ g2b,
    const float* __restrict__ W1,  const float* __restrict__ W2,
    float* __restrict__ We1, float* __restrict__ We2)
{
  __shared__ __align__(16) float sQ[128];    // Q[:, col]
  __shared__ __align__(16) float sRQ[128];   // r*Q
  __shared__ __align__(16) float sT2b[128];  // gU2 @ rq
  const int layer = blockIdx.x >> 7;
  const int col = blockIdx.x & 127;
  const int t = threadIdx.x;
  const int r = t & 127;
  const int h = t >> 7;
  const float4* gW4 = (const float4*)(layer ? g2W : g1W);
  const float4* gU4 = (const float4*)(layer ? g2U : g1U);
  const float*  gb  = layer ? g2b : g1b;
  const float*  W0  = layer ? W2  : W1;
  float* We = layer ? We2 : We1;

  // cache matrix rows in VGPRs (fully unrolled -> static reg indexing)
  float4 mA[32], mB[32];
  if (h == 0){
#pragma unroll
    for (int kq = 0; kq < 32; ++kq){
      float4 a = gW4[0*4096 + r*32 + kq];
      float4 u = gU4[0*4096 + r*32 + kq];
      a.x+=u.x; a.y+=u.y; a.z+=u.z; a.w+=u.w;
      mA[kq] = a;
      mB[kq] = gW4[2*4096 + r*32 + kq];
    }
  } else {
#pragma unroll
    for (int kq = 0; kq < 32; ++kq){
      float4 a = gW4[1*4096 + r*32 + kq];
      float4 u = gU4[1*4096 + r*32 + kq];
      a.x+=u.x; a.y+=u.y; a.z+=u.z; a.w+=u.w;
      mA[kq] = a;
      mB[kq] = gU4[2*4096 + r*32 + kq];
    }
  }
  const float bX = gb[(h ? 1 : 0)*16384 + r*128 + col];
  const float bY = (h == 0) ? gb[2*16384 + r*128 + col] : 0.f;

  if (h == 0) sQ[r] = W0[r*128 + col];
  __syncthreads();

  for (int it = 0; it < 4; ++it){
    // pass 1: h0 -> T0[r] (kept in reg), h1 -> T1[r] -> sRQ
    float tA = dotS(mA, sQ);
    if (h == 1){
      float rr = 1.f/(1.f + expf(-(tA + bX)));
      sRQ[r] = rr * sQ[r];
    }
    __syncthreads();
    // pass 2: h0 -> t2a = gW2@q, h1 -> t2b = gU2@rq
    float tB = dotS(mB, (h == 0) ? sQ : sRQ);
    if (h == 1) sT2b[r] = tB;
    __syncthreads();
    if (h == 0){
      float z = 1.f/(1.f + expf(-(tA + bX)));
      float q = sQ[r];
      sQ[r] = (1.f - z)*q + z*tanhf(tB + sT2b[r] + bY);
    }
    __syncthreads();
  }
  if (h == 0) We[r*128 + col] = sQ[r];
}

// ---------------------------------------------------------------------------
// GEMM: Y[nrows x 128] = X[nrows x 128] @ W[128 x 128], fp32 vector ALU.
// Grid 196 blocks; each grid-strides over 128-row tiles and stages W once.
// (round-15 inner loop: measured best at ~26 us/dispatch)
// ---------------------------------------------------------------------------
__device__ __forceinline__ int wperm(int c){
  return ((c >> 1) & 7) | ((c & 1) << 3) | ((c >> 4) << 4);
}

#define GEMM_NB 196

__global__ __launch_bounds__(512) void gemm_kernel(
    const float* __restrict__ X, const float* __restrict__ W,
    float* __restrict__ Y, int nrows)
{
  __shared__ float4 sX4[128*33];   // row stride 132 floats
  __shared__ float4 sW4[128*32];
  const int tid = threadIdx.x;
  const int rg = tid >> 4;
  const int cg_ = tid & 15;

  const float4* X4 = (const float4*)X;
  const float4* W4 = (const float4*)W;
#pragma unroll
  for (int s = 0; s < 8; ++s){
    int g4 = tid + 512*s;
    int k = g4 >> 5, c = g4 & 31;
    sW4[k*32 + wperm(c)] = W4[g4];
  }

  const float* sXf = (const float*)sX4;
  const int slotA = (cg_ & 7) | ((cg_ >> 3) << 4);
  const int slotB = slotA | 8;
  const int ntiles = (nrows + 127) >> 7;
  float4* Y4 = (float4*)Y;

  for (int tile = blockIdx.x; tile < ntiles; tile += gridDim.x){
    const int rbase = tile << 7;
    if (tile != blockIdx.x) __syncthreads();   // prior compute done before restage
#pragma unroll
    for (int s = 0; s < 8; ++s){
      int g4 = tid + 512*s;
      int r = g4 >> 5, c = g4 & 31;
      float4 v = make_float4(0.f,0.f,0.f,0.f);
      int row = rbase + r;
      if (row < nrows) v = X4[(size_t)row*32 + c];
      sX4[r*33 + c] = v;
    }
    __syncthreads();

    float acc[4][8];
#pragma unroll
    for (int a = 0; a < 4; ++a)
#pragma unroll
      for (int b = 0; b < 8; ++b) acc[a][b] = 0.f;

#pragma unroll 8
    for (int k = 0; k < 128; ++k){
      float4 wa = sW4[k*32 + slotA];
      float4 wb = sW4[k*32 + slotB];
#pragma unroll
      for (int rr = 0; rr < 4; ++rr){
        float xv = sXf[(rg*4 + rr)*132 + k];
        acc[rr][0] = fmaf(xv, wa.x, acc[rr][0]);
        acc[rr][1] = fmaf(xv, wa.y, acc[rr][1]);
        acc[rr][2] = fmaf(xv, wa.z, acc[rr][2]);
        acc[rr][3] = fmaf(xv, wa.w, acc[rr][3]);
        acc[rr][4] = fmaf(xv, wb.x, acc[rr][4]);
        acc[rr][5] = fmaf(xv, wb.y, acc[rr][5]);
        acc[rr][6] = fmaf(xv, wb.z, acc[rr][6]);
        acc[rr][7] = fmaf(xv, wb.w, acc[rr][7]);
      }
    }

#pragma unroll
    for (int rr = 0; rr < 4; ++rr){
      int row = rbase + rg*4 + rr;
      if (row < nrows){
        Y4[(size_t)row*32 + cg_*2 + 0] = make_float4(acc[rr][0],acc[rr][1],acc[rr][2],acc[rr][3]);
        Y4[(size_t)row*32 + cg_*2 + 1] = make_float4(acc[rr][4],acc[rr][5],acc[rr][6],acc[rr][7]);
      }
    }
  }
}

// ---------------------------------------------------------------------------
// Edge binning into fixed-CAP bins, atomic/store split (no scans).
// ---------------------------------------------------------------------------
__global__ __launch_bounds__(256) void hist_kernel(const int* __restrict__ row,
                                                   int* __restrict__ counts, int* __restrict__ slot){
  int base = blockIdx.x*1024 + threadIdx.x;
#pragma unroll
  for (int s = 0; s < 4; ++s){
    int e = base + 256*s;
    if (e < NE){
      int r = row[e];
      int rk = atomicAdd(&counts[r], 1);
      slot[e] = (rk < CAP) ? ((r << 6) + rk) : -1;
    }
  }
}

__global__ __launch_bounds__(256) void scatter_kernel(const int* __restrict__ col,
                                                      const float* __restrict__ val, const int* __restrict__ slot,
                                                      int2* __restrict__ sEdge){
  int base = blockIdx.x*1024 + threadIdx.x;
  int e[4], sl[4];
  bool ok[4];
#pragma unroll
  for (int s = 0; s < 4; ++s){
    e[s] = base + 256*s;
    ok[s] = e[s] < NE;
    sl[s] = ok[s] ? slot[e[s]] : -1;
  }
#pragma unroll
  for (int s = 0; s < 4; ++s){
    if (sl[s] >= 0){
      int2 pk;
      pk.x = col[e[s]];
      pk.y = __float_as_int(val[e[s]]);
      sEdge[sl[s]] = pk;
    }
  }
}

// ---------------------------------------------------------------------------
// SpMM: 2 rows per wave. Half-wave (32 lanes x float4) covers a 512B row.
// 8-deep unroll keeps 8KB of gathers in flight per wave. Bins are contiguous
// CAP-slot runs at r*CAP. rrelu fused into writeback.
// ---------------------------------------------------------------------------
__global__ __launch_bounds__(256) void spmm_kernel(const int* __restrict__ counts, const int2* __restrict__ sEdge,
                                                   const float* __restrict__ Y, float* __restrict__ out){
  const int w = threadIdx.x >> 6;          // wave in block (0..3)
  const int lane = threadIdx.x & 63;
  const int half = lane >> 5;              // which row of the pair
  const int l32 = lane & 31;               // float4 slot within row
  const int r = blockIdx.x*8 + w*2 + half;
  if (r >= NN) return;
  int cnt = counts[r];
  if (cnt > CAP) cnt = CAP;
  const int e0 = r << 6;
  const int e1 = e0 + cnt;
  const float4* __restrict__ Y4 = (const float4*)Y;
  float4 acc = make_float4(0.f, 0.f, 0.f, 0.f);
  int e = e0;
  for (; e + 8 <= e1; e += 8){
    int2 p0 = sEdge[e+0], p1 = sEdge[e+1], p2 = sEdge[e+2], p3 = sEdge[e+3];
    int2 p4 = sEdge[e+4], p5 = sEdge[e+5], p6 = sEdge[e+6], p7 = sEdge[e+7];
    float4 y0 = Y4[(size_t)p0.x*32 + l32];
    float4 y1 = Y4[(size_t)p1.x*32 + l32];
    float4 y2 = Y4[(size_t)p2.x*32 + l32];
    float4 y3 = Y4[(size_t)p3.x*32 + l32];
    float4 y4 = Y4[(size_t)p4.x*32 + l32];
    float4 y5 = Y4[(size_t)p5.x*32 + l32];
    float4 y6 = Y4[(size_t)p6.x*32 + l32];
    float4 y7 = Y4[(size_t)p7.x*32 + l32];
    fma4(__int_as_float(p0.y), y0, acc);
    fma4(__int_as_float(p1.y), y1, acc);
    fma4(__int_as_float(p2.y), y2, acc);
    fma4(__int_as_float(p3.y), y3, acc);
    fma4(__int_as_float(p4.y), y4, acc);
    fma4(__int_as_float(p5.y), y5, acc);
    fma4(__int_as_float(p6.y), y6, acc);
    fma4(__int_as_float(p7.y), y7, acc);
  }
  for (; e + 4 <= e1; e += 4){
    int2 p0 = sEdge[e+0], p1 = sEdge[e+1], p2 = sEdge[e+2], p3 = sEdge[e+3];
    float4 y0 = Y4[(size_t)p0.x*32 + l32];
    float4 y1 = Y4[(size_t)p1.x*32 + l32];
    float4 y2 = Y4[(size_t)p2.x*32 + l32];
    float4 y3 = Y4[(size_t)p3.x*32 + l32];
    fma4(__int_as_float(p0.y), y0, acc);
    fma4(__int_as_float(p1.y), y1, acc);
    fma4(__int_as_float(p2.y), y2, acc);
    fma4(__int_as_float(p3.y), y3, acc);
  }
  for (; e < e1; ++e){
    int2 pk = sEdge[e];
    float4 y = Y4[(size_t)pk.x*32 + l32];
    fma4(__int_as_float(pk.y), y, acc);
  }
  float4 o;
  o.x = (acc.x >= 0.f) ? acc.x : acc.x * SLOPE;
  o.y = (acc.y >= 0.f) ? acc.y : acc.y * SLOPE;
  o.z = (acc.z >= 0.f) ? acc.z : acc.z * SLOPE;
  o.w = (acc.w >= 0.f) ? acc.w : acc.w * SLOPE;
  ((float4*)out)[(size_t)r*32 + l32] = o;
}

// ---------------------------------------------------------------------------
extern "C" void kernel_launch(void* const* d_in, const int* in_sizes, int n_in,
                              void* d_out, int out_size, void* d_ws, size_t ws_size,
                              hipStream_t stream)
{
  const float* features = (const float*)d_in[0];
  const int*   adj_row  = (const int*)d_in[1];
  const int*   adj_col  = (const int*)d_in[2];
  const float* adj_val  = (const float*)d_in[3];
  const float* W1  = (const float*)d_in[4];
  const float* g1W = (const float*)d_in[5];
  const float* g1U = (const float*)d_in[6];
  const float* g1b = (const float*)d_in[7];
  const float* W2  = (const float*)d_in[8];
  const float* g2W = (const float*)d_in[9];
  const float* g2U = (const float*)d_in[10];
  const float* g2b = (const float*)d_in[11];

  // only timestep T-1 ever reaches the output
  const float* feat3 = features + (size_t)3*NN*KD;
  const int*   row3  = adj_row + (size_t)3*NE;
  const int*   col3  = adj_col + (size_t)3*NE;
  const float* val3  = adj_val + (size_t)3*NE;

  float* ws    = (float*)d_ws;
  float* W1e   = ws;                      // 16384 f
  float* W2e   = W1e + 16384;             // 16384 f
  int* counts  = (int*)(W2e + 16384);     // 50000 (padded 50016)
  int* slot    = counts + 50016;          // 800000
  int2* sEdge  = (int2*)(slot + NE);      // 50000*64 x 8B = 25.6 MB (8B-aligned)
  float* XW    = (float*)(sEdge + (size_t)NN*CAP);  // 25.6 MB
  float* outF  = (float*)d_out;

  hipMemsetAsync(counts, 0, NN*sizeof(int), stream);
  hist_kernel<<<(NE + 1023)/1024, 256, 0, stream>>>(row3, counts, slot);
  scatter_kernel<<<(NE + 1023)/1024, 256, 0, stream>>>(col3, val3, slot, sEdge);

  // GRU^4 on both layers' weights: ONE kernel, one block per (layer, column).
  evolve_fused_kernel<<<256, 256, 0, stream>>>(g1W,g1U,g2W,g2U,g1b,g2b, W1,W2, W1e,W2e);

  gemm_kernel<<<GEMM_NB, 512, 0, stream>>>(feat3, W1e, XW, NN);            // X3 @ W1e
  spmm_kernel<<<(NN + 7)/8, 256, 0, stream>>>(counts, sEdge, XW, outF);    // h1 -> d_out
  gemm_kernel<<<GEMM_NB, 512, 0, stream>>>(outF, W2e, XW, NN);             // h1 @ W2e
  spmm_kernel<<<(NN + 7)/8, 256, 0, stream>>>(counts, sEdge, XW, outF);    // final -> d_out
}